// Round 6
// baseline (1920.372 us; speedup 1.0000x reference)
//
#include <hip/hip_runtime.h>
#include <stdint.h>

// SymmetricContraction (MACE) on MI355X, fp32 I/O.
// R6: exploit full symmetry of the contraction in (i,j,l):
//   out[m] = sum_{a<=b<=c} S3[m,abc] x_a x_b x_c + sum_{a<=b} S2[m,ab] x_a x_b
//            + sum_a S1[m,a] x_a
// Table shrinks 4096 -> 816 (1040 with 4-padding) per m; FLOPs ~3.6x less.
// Phases: symU (fold U into sym form) -> tabbuild (per-(e,chan) tables, 24.6MB,
// built once) -> sc_main (block=(chan,e), wave=mhat, NT=4 nodes/lane, x staged
// once in LDS, table via wave-uniform scalar loads) -> finalize (transpose).

#define BN 2048
#define CN 128
#define EN 10

constexpr int LPAD(int b) { return 4 * (b / 4 + 1); }
constexpr int rowStart(int c, int b) {
    int s = 0;
    for (int cc = 0; cc < c; ++cc)
        for (int bb = 0; bb <= cc; ++bb) s += LPAD(bb);
    for (int bb = 0; bb < b; ++bb) s += LPAD(bb);
    return s;
}
constexpr int TP3 = rowStart(15, 15) + LPAD(15);   // 1040
static_assert(TP3 == 1040, "pad math");
#define ROWLEN 1200            // TP3 + 136 + 16 + pad8
#define T2OFF 1040
#define T1OFF 1176

// float offsets in ws
#define OFF_SRC 4096
#define OFF_TAB (OFF_SRC + 4 * ROWLEN * 36)          // 4*1200*36 = 172800
#define OFF_OUT (OFF_TAB + EN * CN * 4 * ROWLEN)     // 10*128*4800 = 6,144,000
// end = OFF_OUT + 512*2048 ~= 29.5 MB

// ints: wsI[0..9]=counts, wsI[16..25]=starts, wsI[32..]=plist
__global__ void compact_kernel(const float* __restrict__ yg, int* __restrict__ wsI) {
    __shared__ int cnt_s[EN], cur_s[EN], start_s[EN];
    const int tid = threadIdx.x;
    if (tid < EN) cnt_s[tid] = 0;
    __syncthreads();
    for (int b = tid; b < BN; b += 256) {
#pragma unroll
        for (int e = 0; e < EN; ++e)
            if (yg[b * EN + e] > 0.5f) { atomicAdd(&cnt_s[e], 1); break; }
    }
    __syncthreads();
    if (tid == 0) {
        int run = 0;
        for (int e = 0; e < EN; ++e) { start_s[e] = run; run += cnt_s[e]; }
    }
    __syncthreads();
    if (tid < EN) {
        cur_s[tid] = start_s[tid];
        wsI[tid] = cnt_s[tid];
        wsI[16 + tid] = start_s[tid];
    }
    __syncthreads();
    for (int b = tid; b < BN; b += 256) {
#pragma unroll
        for (int e = 0; e < EN; ++e)
            if (yg[b * EN + e] > 0.5f) {
                int p = atomicAdd(&cur_s[e], 1);
                wsI[32 + p] = b;
                break;
            }
    }
}

// ---- symU: SRC[mhat][r<1200][k<36]; zero-padded everywhere not real.
__global__ void symU_kernel(
    const float* __restrict__ U3_0, const float* __restrict__ U2_0,
    const float* __restrict__ U1_0, const float* __restrict__ U3_1,
    const float* __restrict__ U2_1, const float* __restrict__ U1_1,
    float* __restrict__ fw)
{
    const int r = blockIdx.x;      // 0..1199
    const int mhat = blockIdx.y;   // 0..3
    const int k = threadIdx.x;     // 0..63
    if (k >= 36) return;
    const int m = (mhat == 0) ? 0 : (mhat - 1);
    const int K3 = (mhat == 0) ? 23 : 33;
    const int K2 = (mhat == 0) ? 4 : 5;
    const float* U3 = (mhat == 0) ? U3_0 : U3_1;
    const float* U2 = (mhat == 0) ? U2_0 : U2_1;
    const float* U1 = (mhat == 0) ? U1_0 : U1_1;
    float v = 0.f;
    if (r < TP3) {
        int cc = -1, bb = -1, off = 0, acc0 = 0;
        for (int c_ = 0; c_ < 16; ++c_)
            for (int b_ = 0; b_ <= c_; ++b_) {
                const int L = LPAD(b_);
                if (r >= acc0 && r < acc0 + L) { cc = c_; bb = b_; off = r - acc0; }
                acc0 += L;
            }
        if (off <= bb && k < K3) {
            const int a_ = off, b_ = bb, c_ = cc;
            int P[6][3] = {{a_, b_, c_}, {a_, c_, b_}, {b_, a_, c_},
                           {b_, c_, a_}, {c_, a_, b_}, {c_, b_, a_}};
            for (int p = 0; p < 6; ++p) {
                bool dup = false;
                for (int q = 0; q < p; ++q)
                    dup |= (P[q][0] == P[p][0] && P[q][1] == P[p][1] && P[q][2] == P[p][2]);
                if (!dup)
                    v += U3[(size_t)(((m * 16 + P[p][0]) * 16 + P[p][1]) * 16 + P[p][2]) * K3 + k];
            }
        }
    } else if (r < TP3 + 136) {
        const int p = r - TP3;
        int c_ = 0;
        while ((c_ + 1) * (c_ + 2) / 2 <= p) ++c_;
        const int b_ = p - c_ * (c_ + 1) / 2;
        if (k < K2) {
            v = U2[(size_t)((m * 16 + b_) * 16 + c_) * K2 + k];
            if (b_ != c_) v += U2[(size_t)((m * 16 + c_) * 16 + b_) * K2 + k];
        }
    } else if (r < TP3 + 136 + 16) {
        const int c_ = r - (TP3 + 136);
        if (k == 0) v = U1[m * 16 + c_];
    }
    fw[OFF_SRC + ((size_t)mhat * ROWLEN + r) * 36 + k] = v;
}

// ---- tabbuild: grid (5 tiles, 4 mhat, 10 e), 128 thr (chan).
// tab[e][chan][mhat][1200]; LDS transpose -> full-line 64B writes per chan.
__global__ __launch_bounds__(128) void tabbuild_kernel(
    const float* __restrict__ W3_0, const float* __restrict__ W2_0,
    const float* __restrict__ W1_0, const float* __restrict__ W3_1,
    const float* __restrict__ W2_1, const float* __restrict__ W1_1,
    float* __restrict__ fw)
{
    const int tile = blockIdx.x;   // 0..4, 240 rows each
    const int mhat = blockIdx.y;
    const int e = blockIdx.z;
    const int chan = threadIdx.x;
    const int K3 = (mhat == 0) ? 23 : 33;
    const int K2 = (mhat == 0) ? 4 : 5;
    const float* W3 = (mhat == 0) ? W3_0 : W3_1;
    const float* W2 = (mhat == 0) ? W2_0 : W2_1;
    const float* W1 = (mhat == 0) ? W1_0 : W1_1;

    float w3[33], w2[5];
#pragma unroll
    for (int k = 0; k < 33; ++k) w3[k] = (k < K3) ? W3[(e * K3 + k) * CN + chan] : 0.f;
#pragma unroll
    for (int k = 0; k < 5; ++k) w2[k] = (k < K2) ? W2[(e * K2 + k) * CN + chan] : 0.f;
    const float w1 = W1[e * CN + chan];

    const float* SRC = fw + OFF_SRC + (size_t)mhat * ROWLEN * 36;
    float* tabO = fw + OFF_TAB;
    __shared__ float trans[128 * 17];

    for (int g = 0; g < 15; ++g) {   // 15 groups x 16 rows
        const int r0 = tile * 240 + g * 16;
        float res[16];
#pragma unroll
        for (int rr = 0; rr < 16; ++rr) {
            const int r = r0 + rr;
            const float* row = SRC + (size_t)r * 36;
            float acc = 0.f;
            if (r < TP3) {
#pragma unroll
                for (int k = 0; k < 33; ++k) acc = fmaf(row[k], w3[k], acc);
            } else if (r < T1OFF) {
#pragma unroll
                for (int k = 0; k < 5; ++k) acc = fmaf(row[k], w2[k], acc);
            } else if (r < T1OFF + 16) {
                acc = row[0] * w1;
            }
            res[rr] = acc;
        }
#pragma unroll
        for (int rr = 0; rr < 16; ++rr) trans[chan * 17 + rr] = res[rr];
        __syncthreads();
#pragma unroll
        for (int s = 0; s < 4; ++s) {
            const int cc = s * 32 + (chan >> 2);
            const int q = chan & 3;
            float4 v = make_float4(trans[cc * 17 + q * 4], trans[cc * 17 + q * 4 + 1],
                                   trans[cc * 17 + q * 4 + 2], trans[cc * 17 + q * 4 + 3]);
            *(float4*)(tabO + (size_t)(e * CN + cc) * (4 * ROWLEN) +
                       (size_t)mhat * ROWLEN + r0 + q * 4) = v;
        }
        __syncthreads();
    }
}

// ---- sc_main: block (chan, e); wave = mhat; NT=4 nodes/lane.
__global__ __launch_bounds__(256, 4) void sc_main(
    const float* __restrict__ xg, const float* __restrict__ fw,
    const int* __restrict__ wsI)
{
    const int chan = blockIdx.x;
    const int e = blockIdx.y;
    const int tid = threadIdx.x;
    const int lane = tid & 63;
    const int wave = __builtin_amdgcn_readfirstlane(tid >> 6);   // = mhat

    const float* T = fw + OFF_TAB + (size_t)(e * CN + chan) * (4 * ROWLEN) +
                     (size_t)wave * ROWLEN;   // wave-uniform -> scalar loads
    __shared__ float xs[16 * 256];

    const int cnt = wsI[e];
    const int start = wsI[16 + e];
    const int* list = wsI + 32 + start;
    float* outws = (float*)(fw + OFF_OUT);
    const int col = (wave == 0) ? chan : (CN + chan * 3 + (wave - 1));

    for (int base = 0; base < cnt; base += 256) {
        {   // stage x transposed: xs[i][slot]
            const int slot = base + tid;
            const int n = (slot < cnt) ? list[slot] : list[cnt - 1];
            const float4* xp = (const float4*)(xg + ((size_t)n * CN + chan) * 16);
            const float4 a0 = xp[0], a1 = xp[1], a2 = xp[2], a3 = xp[3];
            float v[16];
            v[0] = a0.x; v[1] = a0.y; v[2] = a0.z; v[3] = a0.w;
            v[4] = a1.x; v[5] = a1.y; v[6] = a1.z; v[7] = a1.w;
            v[8] = a2.x; v[9] = a2.y; v[10] = a2.z; v[11] = a2.w;
            v[12] = a3.x; v[13] = a3.y; v[14] = a3.z; v[15] = a3.w;
#pragma unroll
            for (int i = 0; i < 16; ++i) xs[i * 256 + tid] = v[i];
        }
        __syncthreads();

        float x[4][16];
#pragma unroll
        for (int t = 0; t < 4; ++t)
#pragma unroll
            for (int i = 0; i < 16; ++i) x[t][i] = xs[i * 256 + t * 64 + lane];

        float acc[4] = {0.f, 0.f, 0.f, 0.f};
#pragma unroll
        for (int c = 0; c < 16; ++c) {
            const float g0 = T[T1OFF + c];
            float G[4] = {g0, g0, g0, g0};
#pragma unroll
            for (int b = 0; b <= c; ++b) {
                const float hh = T[T2OFF + c * (c + 1) / 2 + b];
                float H[4] = {hh, hh, hh, hh};
#pragma unroll
                for (int q = 0; q <= b / 4; ++q) {
                    const float4 r = *(const float4*)(T + rowStart(c, b) + q * 4);
#pragma unroll
                    for (int t = 0; t < 4; ++t) {
                        H[t] = fmaf(r.x, x[t][q * 4 + 0], H[t]);
                        H[t] = fmaf(r.y, x[t][q * 4 + 1], H[t]);
                        H[t] = fmaf(r.z, x[t][q * 4 + 2], H[t]);
                        H[t] = fmaf(r.w, x[t][q * 4 + 3], H[t]);
                    }
                }
#pragma unroll
                for (int t = 0; t < 4; ++t) G[t] = fmaf(x[t][b], H[t], G[t]);
            }
#pragma unroll
            for (int t = 0; t < 4; ++t) acc[t] = fmaf(x[t][c], G[t], acc[t]);
        }

#pragma unroll
        for (int t = 0; t < 4; ++t) {
            const int slot = base + t * 64 + lane;
            if (slot < cnt) outws[(size_t)col * BN + start + slot] = acc[t];
        }
        __syncthreads();
    }
}

// ---- finalize: outws[col][p] -> out[b][col] via LDS tile.
__global__ __launch_bounds__(256) void finalize(
    const float* __restrict__ fw, const int* __restrict__ wsI,
    float* __restrict__ outg)
{
    const int p0 = blockIdx.x * 64;
    const int tid = threadIdx.x;
    __shared__ float buf[64 * 129];
    const float* outws = fw + OFF_OUT;
    for (int c0 = 0; c0 < 512; c0 += 128) {
        for (int idx = tid; idx < 64 * 128; idx += 256) {
            const int pp = idx & 63, cc = idx >> 6;
            buf[pp * 129 + cc] = outws[(size_t)(c0 + cc) * BN + p0 + pp];
        }
        __syncthreads();
        for (int idx = tid; idx < 64 * 128; idx += 256) {
            const int cc = idx & 127, pp = idx >> 7;
            outg[(size_t)wsI[32 + p0 + pp] * 512 + c0 + cc] = buf[pp * 129 + cc];
        }
        __syncthreads();
    }
}

extern "C" void kernel_launch(void* const* d_in, const int* in_sizes, int n_in,
                              void* d_out, int out_size, void* d_ws, size_t ws_size,
                              hipStream_t stream) {
    const float* x = (const float*)d_in[0];
    const float* y = (const float*)d_in[1];
    const float* U3_0 = (const float*)d_in[2];
    const float* U2_0 = (const float*)d_in[3];
    const float* U1_0 = (const float*)d_in[4];
    const float* W3_0 = (const float*)d_in[5];
    const float* W2_0 = (const float*)d_in[6];
    const float* W1_0 = (const float*)d_in[7];
    const float* U3_1 = (const float*)d_in[8];
    const float* U2_1 = (const float*)d_in[9];
    const float* U1_1 = (const float*)d_in[10];
    const float* W3_1 = (const float*)d_in[11];
    const float* W2_1 = (const float*)d_in[12];
    const float* W1_1 = (const float*)d_in[13];
    float* out = (float*)d_out;
    float* fw = (float*)d_ws;
    int* wsI = (int*)d_ws;

    compact_kernel<<<1, 256, 0, stream>>>(y, wsI);
    symU_kernel<<<dim3(ROWLEN, 4), 64, 0, stream>>>(U3_0, U2_0, U1_0, U3_1, U2_1, U1_1, fw);
    tabbuild_kernel<<<dim3(5, 4, EN), 128, 0, stream>>>(W3_0, W2_0, W1_0, W3_1, W2_1, W1_1, fw);
    sc_main<<<dim3(CN, EN), 256, 0, stream>>>(x, fw, wsI);
    finalize<<<32, 256, 0, stream>>>(fw, wsI, out);
}